// Round 10
// baseline (240.153 us; speedup 1.0000x reference)
//
#include <hip/hip_runtime.h>
#include <hip/hip_bf16.h>

// B=4096, C=32, P=196, ENC=512, ATT=128. fp32 I/O.
// k1 (U_h/beta GEMM): bf16 hi/lo split -> split-K partials.
// k2: reduces its own uh/beta from partials (k1b deleted); single-bf16 score
// path; img bf16-RNE in LDS (18 KB -> 8 blocks/CU); W frags hoisted to regs;
// W_w/uh pre-scaled by K2E so tanh = 1 - 2*rcp(1+exp2(d)); unnormalized
// softmax, one divide at the end.
// LESSONS: (R5/R6) waves/EU >= 6 in launch_bounds => scratch-spill storm;
// (256,4) is the no-spill point. (R8) __hip_bfloat162 not trivially copyable.
// (R9) harness ws-poison (60us) + input restore (~40us) sit inside the timed
// window -- kernel-side budget is only ~95us of the ~205 total.

typedef __attribute__((ext_vector_type(8))) short short8;
typedef __attribute__((ext_vector_type(8))) __bf16 bf16x8;
typedef __attribute__((ext_vector_type(4))) float floatx4;
typedef __attribute__((ext_vector_type(4))) unsigned int uint4v;

#define K2E 2.8853900817779268f   // 2*log2(e)

#if __has_builtin(__builtin_amdgcn_exp2f)
#define EXP2F(x) __builtin_amdgcn_exp2f(x)
#else
#define EXP2F(x) __expf(0.6931471805599453f * (x))
#endif

static __device__ __forceinline__ float bf2f(unsigned short u) {
    union { unsigned int i; float f; } v; v.i = ((unsigned int)u) << 16; return v.f;
}
static __device__ __forceinline__ unsigned short f2bf(float f) {
    union { float f; unsigned int i; } v; v.f = f;
    unsigned int r = v.i + 0x7FFFu + ((v.i >> 16) & 1u);  // RNE
    return (unsigned short)(r >> 16);
}
static __device__ __forceinline__ float sigmoid_rcp(float x) {
    return __builtin_amdgcn_rcpf(1.0f + __expf(-x));
}
// Truncation hi/lo split of 8 contiguous fp32 (16B-aligned) - k1 only.
static __device__ __forceinline__ void split_trunc8(const float* src, bf16x8* hi, bf16x8* lo) {
    uint4v u0 = *(const uint4v*)src;
    uint4v u1 = *(const uint4v*)(src + 4);
    unsigned int fb[8], lb[8];
#pragma unroll
    for (int j = 0; j < 4; j++) { fb[j] = u0[j]; fb[4 + j] = u1[j]; }
#pragma unroll
    for (int k = 0; k < 8; k++) {
        float x = __uint_as_float(fb[k]);
        float h = __uint_as_float(fb[k] & 0xFFFF0000u);
        lb[k] = __float_as_uint(x - h);               // exact
    }
    uint4v hp, lp;
#pragma unroll
    for (int j = 0; j < 4; j++) {
        hp[j] = __builtin_amdgcn_perm(fb[2 * j + 1], fb[2 * j], 0x07060302u);
        lp[j] = __builtin_amdgcn_perm(lb[2 * j + 1], lb[2 * j], 0x07060302u);
    }
    *hi = __builtin_bit_cast(bf16x8, hp);
    *lo = __builtin_bit_cast(bf16x8, lp);
}

// ---------------------------------------------------------------------------
// k0: RNE hi/lo split U_w ++ fb_w -> Bhi/Blo; RNE hi-only K2E*W_w -> Whi
// ---------------------------------------------------------------------------
__global__ __launch_bounds__(256) void k0_split(
    const float* __restrict__ U_w, const float* __restrict__ fb_w,
    const float* __restrict__ W_w,
    unsigned short* __restrict__ Bhi, unsigned short* __restrict__ Blo,
    unsigned short* __restrict__ Whi)
{
    int i = blockIdx.x * 256 + threadIdx.x;  // 0..86015
    if (i < 81920) {
        float x = (i < 65536) ? U_w[i] : fb_w[i - 65536];
        unsigned short h = f2bf(x);
        Bhi[i] = h;
        Blo[i] = f2bf(x - bf2f(h));
    } else {
        Whi[i - 81920] = f2bf(W_w[i - 81920] * K2E);
    }
}

// ---------------------------------------------------------------------------
// k1: partial GEMM hidden @ [U_w;fb_w]^T with split-K (ws-gated), hi/lo.
// direct=1 (fallback): full K, writes scaled uh + sigmoid beta directly.
// ---------------------------------------------------------------------------
__global__ __launch_bounds__(256) void k1_gemm(
    const float* __restrict__ hidden,
    const unsigned short* __restrict__ Bhi, const unsigned short* __restrict__ Blo,
    const float* __restrict__ U_b, const float* __restrict__ W_b,
    const float* __restrict__ fb_b,
    float* __restrict__ uh_out, float* __restrict__ beta_out,
    float* __restrict__ partial, int nsplit, int direct)
{
    __shared__ float s_part[4 * 2560];
    const int tid = threadIdx.x;
    const int wave = tid >> 6, lane = tid & 63, quad = lane >> 4, l16 = lane & 15;
    const int mtile = blockIdx.x / nsplit;
    const int kblock = 512 / nsplit;
    const int ks0 = (blockIdx.x % nsplit) * kblock + wave * (kblock >> 2);
    const int ksteps = kblock >> 7;
    const int arow = mtile * 16 + l16;

    floatx4 acc[10];
#pragma unroll
    for (int i = 0; i < 10; i++) acc[i] = (floatx4)(0.0f);

    for (int ksi = 0; ksi < ksteps; ksi++) {
        const int e0 = ks0 + ksi * 32 + quad * 8;
        bf16x8 ah, al;
        split_trunc8(hidden + (size_t)arow * 512 + e0, &ah, &al);
#pragma unroll
        for (int n = 0; n < 10; n++) {
            const size_t bo = (size_t)(n * 16 + l16) * 512 + e0;
            bf16x8 bh = *(const bf16x8*)(Bhi + bo);
            bf16x8 bl = *(const bf16x8*)(Blo + bo);
            acc[n] = __builtin_amdgcn_mfma_f32_16x16x32_bf16(ah, bl, acc[n], 0, 0, 0);
            acc[n] = __builtin_amdgcn_mfma_f32_16x16x32_bf16(al, bh, acc[n], 0, 0, 0);
            acc[n] = __builtin_amdgcn_mfma_f32_16x16x32_bf16(ah, bh, acc[n], 0, 0, 0);
        }
    }
#pragma unroll
    for (int n = 0; n < 10; n++)
#pragma unroll
        for (int r = 0; r < 4; r++)
            s_part[wave * 2560 + (quad * 4 + r) * 160 + n * 16 + l16] = acc[n][r];
    __syncthreads();

#pragma unroll
    for (int j = 0; j < 10; j++) {
        const int i = tid + j * 256;
        float v = s_part[i] + s_part[2560 + i] + s_part[5120 + i] + s_part[7680 + i];
        if (direct) {
            const int m = mtile * 16 + i / 160, col = i % 160;
            if (col < 128) uh_out[(size_t)m * 128 + col] = K2E * (v + U_b[col] + W_b[col]);
            else beta_out[(size_t)m * 32 + (col - 128)] = sigmoid_rcp(v + fb_b[col - 128]);
        } else {
            partial[(size_t)blockIdx.x * 2560 + i] = v;
        }
    }
}

// ---------------------------------------------------------------------------
// k2: one block (256 thr) per batch. M=p (13 tiles), N=a (8 tiles), K=c.
// nsplit>0: reduce own uh/beta from partial. nsplit==0: read uh_ws/beta_ws.
// ---------------------------------------------------------------------------
#define HSTR 40    // u16 per LDS img row (32 data + 8 pad; 80 B -> ~2-way banks)

__global__ __launch_bounds__(256, 4) void k2_attn(
    const float* __restrict__ img,            // [4096][32][196]
    const unsigned short* __restrict__ Whi,   // [128][32] bf16 (pre-scaled K2E)
    const float* __restrict__ v_w,            // [128]
    const float* __restrict__ partial,        // [256*nsplit][2560] (nsplit>0)
    const float* __restrict__ uh_ws,          // (nsplit==0) scaled uh
    const float* __restrict__ beta_ws,        // (nsplit==0) sigmoid beta
    const float* __restrict__ U_b, const float* __restrict__ W_b,
    const float* __restrict__ fb_b,
    float* __restrict__ out, int nsplit)
{
    __shared__ __align__(16) unsigned short s_imgh[208 * HSTR];  // 16640 B
    __shared__ float s_score[208];
    __shared__ float s_red[8];
    __shared__ float s_ctx[4][32];

    const int tid = threadIdx.x;
    const int b = blockIdx.x;
    const int wave = tid >> 6, lane = tid & 63, quad = lane >> 4, l16 = lane & 15;

    // ---- uh/beta for this batch row (reduce partials or read ws) ----
    const int mtile = b >> 4, mrow = b & 15;
    float uaR[8], va2R[8], sv = 0.0f, betaR = 0.0f;
    if (nsplit > 0) {
        const float* pb = partial + ((size_t)mtile * nsplit) * 2560 + mrow * 160;
#pragma unroll
        for (int nt = 0; nt < 8; nt++) {
            const int col = nt * 16 + l16;
            float v = 0.0f;
            for (int s = 0; s < nsplit; s++) v += pb[s * 2560 + col];
            uaR[nt] = K2E * (v + U_b[col] + W_b[col]);
        }
        if (tid < 32) {
            float v = 0.0f;
            for (int s = 0; s < nsplit; s++) v += pb[s * 2560 + 128 + tid];
            betaR = sigmoid_rcp(v + fb_b[tid]);
        }
    } else {
#pragma unroll
        for (int nt = 0; nt < 8; nt++)
            uaR[nt] = uh_ws[(size_t)b * 128 + nt * 16 + l16];
        if (tid < 32) betaR = beta_ws[(size_t)b * 32 + tid];
    }
#pragma unroll
    for (int nt = 0; nt < 8; nt++) {
        float v = v_w[nt * 16 + l16];
        sv += v;
        va2R[nt] = -2.0f * v;
    }
    sv += __shfl_xor(sv, 1); sv += __shfl_xor(sv, 2);
    sv += __shfl_xor(sv, 4); sv += __shfl_xor(sv, 8);   // uniform over l16

    // W frags hoisted to regs (32 VGPRs; live set ~90 < 128 @ (256,4))
    bf16x8 bhR[8];
#pragma unroll
    for (int nt = 0; nt < 8; nt++)
        bhR[nt] = *(const bf16x8*)(Whi + (nt * 16 + l16) * 32 + quad * 8);

    // ---- Phase A: transpose-stage img[b] -> LDS bf16-RNE [p][c] ----
    if (tid < 196) {
        const size_t base = (size_t)b * 6272 + tid;
#pragma unroll
        for (int g = 0; g < 4; g++) {
            unsigned int hb[8];
#pragma unroll
            for (int j = 0; j < 8; j++) {
                unsigned int u = __float_as_uint(img[base + (size_t)(8 * g + j) * 196]);
                hb[j] = u + 0x7FFFu + ((u >> 16) & 1u);   // RNE to bf16 in hi16
            }
            uint4v hp;
#pragma unroll
            for (int j = 0; j < 4; j++)
                hp[j] = __builtin_amdgcn_perm(hb[2 * j + 1], hb[2 * j], 0x07060302u);
            *(uint4v*)&s_imgh[tid * HSTR + g * 8] = hp;   // ds_write_b128
        }
    } else {
        for (int i = tid - 196; i < 12 * HSTR; i += 60) s_imgh[196 * HSTR + i] = 0;
        if (tid < 208) s_score[tid] = 0.0f;   // rows 196..207 weight 0 for Phase D
    }
    __syncthreads();   // barrier 1: img + s_score pad ready

    // ---- Phase B: wave w owns p-tiles {w, w+4, w+8 (,12)}; track max ----
    float mloc = -1e30f;
    for (int mt = wave; mt < 13; mt += 4) {
        bf16x8 a = *(const bf16x8*)&s_imgh[(mt * 16 + l16) * HSTR + quad * 8];
        float sc4[4] = {0.f, 0.f, 0.f, 0.f};
#pragma unroll
        for (int nt = 0; nt < 8; nt++) {
            const float ua = uaR[nt];
            floatx4 d = {ua, ua, ua, ua};            // fold Uh(+biases) into C
            d = __builtin_amdgcn_mfma_f32_16x16x32_bf16(a, bhR[nt], d, 0, 0, 0);
#pragma unroll
            for (int r = 0; r < 4; r++) {
                float e = EXP2F(d[r]);                         // e^{2x}
                float rr = __builtin_amdgcn_rcpf(1.0f + e);
                sc4[r] = __builtin_fmaf(va2R[nt], rr, sc4[r]); // -2 v_a r
            }
        }
#pragma unroll
        for (int r = 0; r < 4; r++) {
            float s = sc4[r];
            s += __shfl_xor(s, 1); s += __shfl_xor(s, 2);
            s += __shfl_xor(s, 4); s += __shfl_xor(s, 8);
            const int p = mt * 16 + quad * 4 + r;
            const float x = sv + s;
            if (p < 196) {
                if (l16 == 0) s_score[p] = x;
                mloc = fmaxf(mloc, x);
            }
        }
    }
    // wave-level max
    mloc = fmaxf(mloc, __shfl_xor(mloc, 1));
    mloc = fmaxf(mloc, __shfl_xor(mloc, 2));
    mloc = fmaxf(mloc, __shfl_xor(mloc, 4));
    mloc = fmaxf(mloc, __shfl_xor(mloc, 8));
    mloc = fmaxf(mloc, __shfl_xor(mloc, 16));
    mloc = fmaxf(mloc, __shfl_xor(mloc, 32));
    if (lane == 0) s_red[wave] = mloc;
    __syncthreads();   // barrier 2: scores + per-wave maxima ready

    // ---- Phase C: e = exp(x-m); publish e + per-wave sums in one pass ----
    const float m = fmaxf(fmaxf(s_red[0], s_red[1]), fmaxf(s_red[2], s_red[3]));
    float e = 0.0f;
    if (tid < 196) e = __expf(s_score[tid] - m);
    float ssum = e;
#pragma unroll
    for (int off = 32; off > 0; off >>= 1) ssum += __shfl_xor(ssum, off);
    if (lane == 0) s_red[4 + wave] = ssum;
    if (tid < 196) s_score[tid] = e;          // unnormalized
    __syncthreads();   // barrier 3: e + partial sums ready
    const float tot = s_red[4] + s_red[5] + s_red[6] + s_red[7];
    const float rtot = __builtin_amdgcn_rcpf(tot);
    if (tid < 196)
        out[131072 + (size_t)b * 196 + tid] = e * rtot;   // att_weights

    // ---- Phase D: context[c] = beta[c]/tot * sum_p img[p][c]*e[p] ----
    {
        const int c = lane & 31;
        const int po = wave * 2 + (lane >> 5);   // 0..7
        float acc = 0.0f;
#pragma unroll 5
        for (int j = 0; j < 25; j++) {
            const int p = po + j * 8;            // <=199; rows 196+ zeroed
            acc = __builtin_fmaf(bf2f(s_imgh[p * HSTR + c]), s_score[p], acc);
        }
        acc += __shfl_xor(acc, 32);
        if ((lane >> 5) == 0) s_ctx[wave][c] = acc;
    }
    __syncthreads();   // barrier 4: ctx partials ready
    if (tid < 32) {
        const float v = s_ctx[0][tid] + s_ctx[1][tid] + s_ctx[2][tid] + s_ctx[3][tid];
        out[(size_t)b * 32 + tid] = v * rtot * betaR;
    }
}

extern "C" void kernel_launch(void* const* d_in, const int* in_sizes, int n_in,
                              void* d_out, int out_size, void* d_ws, size_t ws_size,
                              hipStream_t stream) {
    const float* img    = (const float*)d_in[0];
    const float* hidden = (const float*)d_in[1];
    const float* W_w    = (const float*)d_in[2];
    const float* W_b    = (const float*)d_in[3];
    const float* U_w    = (const float*)d_in[4];
    const float* U_b    = (const float*)d_in[5];
    const float* v_w    = (const float*)d_in[6];
    // d_in[7] = v_b: cancels in softmax
    const float* fb_w   = (const float*)d_in[8];
    const float* fb_b   = (const float*)d_in[9];
    float* out = (float*)d_out;

    float* uh_ws   = (float*)d_ws;                                 // 2 MB
    float* beta_ws = uh_ws + 4096 * 128;                           // 0.5 MB
    unsigned short* Bhi = (unsigned short*)(beta_ws + 4096 * 32);  // 160 KB
    unsigned short* Blo = Bhi + 81920;                             // 160 KB
    unsigned short* Whi = Blo + 81920;                             // 8 KB
    float* partial = (float*)(Whi + 4096);
    const size_t fixed_bytes = ((char*)partial) - ((char*)d_ws);

    int nsplit = 0;
    if (ws_size >= fixed_bytes + (size_t)256 * 4 * 2560 * 4) nsplit = 4;
    else if (ws_size >= fixed_bytes + (size_t)256 * 2 * 2560 * 4) nsplit = 2;
    else if (ws_size >= fixed_bytes + (size_t)256 * 1 * 2560 * 4) nsplit = 1;

    k0_split<<<dim3(336), dim3(256), 0, stream>>>(U_w, fb_w, W_w, Bhi, Blo, Whi);
    if (nsplit > 0) {
        k1_gemm<<<dim3(256 * nsplit), dim3(256), 0, stream>>>(
            hidden, Bhi, Blo, U_b, W_b, fb_b, uh_ws, beta_ws, partial, nsplit, 0);
        k2_attn<<<dim3(4096), dim3(256), 0, stream>>>(
            img, Whi, v_w, partial, nullptr, nullptr, U_b, W_b, fb_b, out, nsplit);
    } else {
        k1_gemm<<<dim3(256), dim3(256), 0, stream>>>(
            hidden, Bhi, Blo, U_b, W_b, fb_b, uh_ws, beta_ws, partial, 1, 1);
        k2_attn<<<dim3(4096), dim3(256), 0, stream>>>(
            img, Whi, v_w, nullptr, uh_ws, beta_ws, U_b, W_b, fb_b, out, 0);
    }
}

// Round 11
// 204.697 us; speedup vs baseline: 1.1732x; 1.1732x over previous
//
#include <hip/hip_runtime.h>
#include <hip/hip_bf16.h>

// B=4096, C=32, P=196, ENC=512, ATT=128. fp32 I/O.
// k1 (U_h/beta GEMM): bf16 hi/lo split -> split-K partials; k1b reduces.
// k2: single-bf16 score path; img bf16-RNE in LDS (18 KB -> 8 blocks/CU);
// W read from global (L1-hot) in the nt loop; W_w/uh pre-scaled by K2E so
// tanh = 1 - 2*rcp(1+exp2(d)); MAX-FREE softmax (|score| <= sum|v| ~ 5, so
// exp never overflows) -> Phase B emits e directly, 3 barriers total.
// LESSONS: (R5/R6) launch_bounds waves/EU >= 6 => scratch-spill storm; the
// allocator pins itself to <=64 VGPR here -- structures needing more either
// spill (R5) or silently keep loads in-loop (R10 hoist no-op). (R8)
// __hip_bfloat162 not trivially copyable. (R9) harness ws-poison (60us) +
// input restore (~40us) sit inside the timed window. (R10) per-block
// partial-reduce prologue with runtime loop = +35us latency; keep k1b.

typedef __attribute__((ext_vector_type(8))) short short8;
typedef __attribute__((ext_vector_type(8))) __bf16 bf16x8;
typedef __attribute__((ext_vector_type(4))) float floatx4;
typedef __attribute__((ext_vector_type(4))) unsigned int uint4v;

#define K2E 2.8853900817779268f   // 2*log2(e)

#if __has_builtin(__builtin_amdgcn_exp2f)
#define EXP2F(x) __builtin_amdgcn_exp2f(x)
#else
#define EXP2F(x) __expf(0.6931471805599453f * (x))
#endif

static __device__ __forceinline__ float bf2f(unsigned short u) {
    union { unsigned int i; float f; } v; v.i = ((unsigned int)u) << 16; return v.f;
}
static __device__ __forceinline__ unsigned short f2bf(float f) {
    union { float f; unsigned int i; } v; v.f = f;
    unsigned int r = v.i + 0x7FFFu + ((v.i >> 16) & 1u);  // RNE
    return (unsigned short)(r >> 16);
}
static __device__ __forceinline__ float sigmoid_rcp(float x) {
    return __builtin_amdgcn_rcpf(1.0f + __expf(-x));
}
// Truncation hi/lo split of 8 contiguous fp32 (16B-aligned) - k1 only.
static __device__ __forceinline__ void split_trunc8(const float* src, bf16x8* hi, bf16x8* lo) {
    uint4v u0 = *(const uint4v*)src;
    uint4v u1 = *(const uint4v*)(src + 4);
    unsigned int fb[8], lb[8];
#pragma unroll
    for (int j = 0; j < 4; j++) { fb[j] = u0[j]; fb[4 + j] = u1[j]; }
#pragma unroll
    for (int k = 0; k < 8; k++) {
        float x = __uint_as_float(fb[k]);
        float h = __uint_as_float(fb[k] & 0xFFFF0000u);
        lb[k] = __float_as_uint(x - h);               // exact
    }
    uint4v hp, lp;
#pragma unroll
    for (int j = 0; j < 4; j++) {
        hp[j] = __builtin_amdgcn_perm(fb[2 * j + 1], fb[2 * j], 0x07060302u);
        lp[j] = __builtin_amdgcn_perm(lb[2 * j + 1], lb[2 * j], 0x07060302u);
    }
    *hi = __builtin_bit_cast(bf16x8, hp);
    *lo = __builtin_bit_cast(bf16x8, lp);
}

// ---------------------------------------------------------------------------
// k0: RNE hi/lo split U_w ++ fb_w -> Bhi/Blo; RNE hi-only K2E*W_w -> Whi
// ---------------------------------------------------------------------------
__global__ __launch_bounds__(256) void k0_split(
    const float* __restrict__ U_w, const float* __restrict__ fb_w,
    const float* __restrict__ W_w,
    unsigned short* __restrict__ Bhi, unsigned short* __restrict__ Blo,
    unsigned short* __restrict__ Whi)
{
    int i = blockIdx.x * 256 + threadIdx.x;  // 0..86015
    if (i < 81920) {
        float x = (i < 65536) ? U_w[i] : fb_w[i - 65536];
        unsigned short h = f2bf(x);
        Bhi[i] = h;
        Blo[i] = f2bf(x - bf2f(h));
    } else {
        Whi[i - 81920] = f2bf(W_w[i - 81920] * K2E);
    }
}

// ---------------------------------------------------------------------------
// k1: partial GEMM hidden @ [U_w;fb_w]^T with split-K (ws-gated), hi/lo.
// direct=1 (fallback): full K, writes scaled uh + sigmoid beta directly.
// ---------------------------------------------------------------------------
__global__ __launch_bounds__(256) void k1_gemm(
    const float* __restrict__ hidden,
    const unsigned short* __restrict__ Bhi, const unsigned short* __restrict__ Blo,
    const float* __restrict__ U_b, const float* __restrict__ W_b,
    const float* __restrict__ fb_b,
    float* __restrict__ uh_out, float* __restrict__ beta_out,
    float* __restrict__ partial, int nsplit, int direct)
{
    __shared__ float s_part[4 * 2560];
    const int tid = threadIdx.x;
    const int wave = tid >> 6, lane = tid & 63, quad = lane >> 4, l16 = lane & 15;
    const int mtile = blockIdx.x / nsplit;
    const int kblock = 512 / nsplit;
    const int ks0 = (blockIdx.x % nsplit) * kblock + wave * (kblock >> 2);
    const int ksteps = kblock >> 7;
    const int arow = mtile * 16 + l16;

    floatx4 acc[10];
#pragma unroll
    for (int i = 0; i < 10; i++) acc[i] = (floatx4)(0.0f);

    for (int ksi = 0; ksi < ksteps; ksi++) {
        const int e0 = ks0 + ksi * 32 + quad * 8;
        bf16x8 ah, al;
        split_trunc8(hidden + (size_t)arow * 512 + e0, &ah, &al);
#pragma unroll
        for (int n = 0; n < 10; n++) {
            const size_t bo = (size_t)(n * 16 + l16) * 512 + e0;
            bf16x8 bh = *(const bf16x8*)(Bhi + bo);
            bf16x8 bl = *(const bf16x8*)(Blo + bo);
            acc[n] = __builtin_amdgcn_mfma_f32_16x16x32_bf16(ah, bl, acc[n], 0, 0, 0);
            acc[n] = __builtin_amdgcn_mfma_f32_16x16x32_bf16(al, bh, acc[n], 0, 0, 0);
            acc[n] = __builtin_amdgcn_mfma_f32_16x16x32_bf16(ah, bh, acc[n], 0, 0, 0);
        }
    }
#pragma unroll
    for (int n = 0; n < 10; n++)
#pragma unroll
        for (int r = 0; r < 4; r++)
            s_part[wave * 2560 + (quad * 4 + r) * 160 + n * 16 + l16] = acc[n][r];
    __syncthreads();

#pragma unroll
    for (int j = 0; j < 10; j++) {
        const int i = tid + j * 256;
        float v = s_part[i] + s_part[2560 + i] + s_part[5120 + i] + s_part[7680 + i];
        if (direct) {
            const int m = mtile * 16 + i / 160, col = i % 160;
            if (col < 128) uh_out[(size_t)m * 128 + col] = K2E * (v + U_b[col] + W_b[col]);
            else beta_out[(size_t)m * 32 + (col - 128)] = sigmoid_rcp(v + fb_b[col - 128]);
        } else {
            partial[(size_t)blockIdx.x * 2560 + i] = v;
        }
    }
}

__global__ __launch_bounds__(256) void k1b_reduce(
    const float* __restrict__ partial,
    const float* __restrict__ U_b, const float* __restrict__ W_b,
    const float* __restrict__ fb_b,
    float* __restrict__ uh_out, float* __restrict__ beta_out, int nsplit)
{
    const int idx = blockIdx.x * 256 + threadIdx.x;
    const int mt = idx / 2560, r = idx % 2560;
    float v = 0.0f;
    for (int s = 0; s < nsplit; s++)
        v += partial[(size_t)(mt * nsplit + s) * 2560 + r];
    const int m = mt * 16 + r / 160, col = r % 160;
    if (col < 128) uh_out[(size_t)m * 128 + col] = K2E * (v + U_b[col] + W_b[col]);
    else beta_out[(size_t)m * 32 + (col - 128)] = sigmoid_rcp(v + fb_b[col - 128]);
}

// ---------------------------------------------------------------------------
// k2: one block (256 thr) per batch. M=p (13 tiles), N=a (8 tiles), K=c.
// Max-free softmax: Phase B emits e = exp(score) directly; 3 barriers.
// ---------------------------------------------------------------------------
#define HSTR 40    // u16 per LDS img row (32 data + 8 pad; 80 B -> ~2-way banks)

__global__ __launch_bounds__(256, 4) void k2_attn(
    const float* __restrict__ img,            // [4096][32][196]
    const unsigned short* __restrict__ Whi,   // [128][32] bf16 (pre-scaled K2E)
    const float* __restrict__ v_w,            // [128]
    const float* __restrict__ uh,             // [4096][128] (scaled K2E, biases in)
    const float* __restrict__ beta,           // [4096][32]
    float* __restrict__ out)
{
    __shared__ __align__(16) unsigned short s_imgh[208 * HSTR];  // 16640 B
    __shared__ float s_score[208];   // holds e[p] (unnormalized softmax)
    __shared__ float s_red[4];
    __shared__ float s_ctx[4][32];

    const int tid = threadIdx.x;
    const int b = blockIdx.x;
    const int wave = tid >> 6, lane = tid & 63, quad = lane >> 4, l16 = lane & 15;

    // ---- Phase A: transpose-stage img[b] -> LDS bf16-RNE [p][c] ----
    if (tid < 196) {
        const size_t base = (size_t)b * 6272 + tid;
#pragma unroll
        for (int g = 0; g < 4; g++) {
            unsigned int hb[8];
#pragma unroll
            for (int j = 0; j < 8; j++) {
                unsigned int u = __float_as_uint(img[base + (size_t)(8 * g + j) * 196]);
                hb[j] = u + 0x7FFFu + ((u >> 16) & 1u);   // RNE to bf16 in hi16
            }
            uint4v hp;
#pragma unroll
            for (int j = 0; j < 4; j++)
                hp[j] = __builtin_amdgcn_perm(hb[2 * j + 1], hb[2 * j], 0x07060302u);
            *(uint4v*)&s_imgh[tid * HSTR + g * 8] = hp;   // ds_write_b128
        }
    } else {
        for (int i = tid - 196; i < 12 * HSTR; i += 60) s_imgh[196 * HSTR + i] = 0;
        if (tid < 208) s_score[tid] = 0.0f;   // rows 196..207 weight 0 for Phase D
    }

    // per-lane uh (scaled) and v; Sv = sum_a v[a]
    float uaR[8], va2R[8], sv = 0.0f;
#pragma unroll
    for (int nt = 0; nt < 8; nt++) {
        uaR[nt] = uh[(size_t)b * 128 + nt * 16 + l16];
        float v = v_w[nt * 16 + l16];
        sv += v;
        va2R[nt] = -2.0f * v;
    }
    sv += __shfl_xor(sv, 1); sv += __shfl_xor(sv, 2);
    sv += __shfl_xor(sv, 4); sv += __shfl_xor(sv, 8);   // uniform over l16
    __syncthreads();   // barrier 1: img + s_score pad ready

    // ---- Phase B: wave w owns p-tiles {w, w+4, w+8 (,12)}; emit e directly.
    // |score| <= sum|v_a| (~5): exp(score) cannot overflow -> no max pass.
    float esum = 0.0f;
    for (int mt = wave; mt < 13; mt += 4) {
        bf16x8 a = *(const bf16x8*)&s_imgh[(mt * 16 + l16) * HSTR + quad * 8];
        float sc4[4] = {0.f, 0.f, 0.f, 0.f};
#pragma unroll
        for (int nt = 0; nt < 8; nt++) {
            bf16x8 bh = *(const bf16x8*)(Whi + (nt * 16 + l16) * 32 + quad * 8);
            const float ua = uaR[nt];
            floatx4 d = {ua, ua, ua, ua};            // fold Uh(+biases) into C
            d = __builtin_amdgcn_mfma_f32_16x16x32_bf16(a, bh, d, 0, 0, 0);
#pragma unroll
            for (int r = 0; r < 4; r++) {
                float e = EXP2F(d[r]);                         // e^{2x}
                float rr = __builtin_amdgcn_rcpf(1.0f + e);
                sc4[r] = __builtin_fmaf(va2R[nt], rr, sc4[r]); // -2 v_a r
            }
        }
#pragma unroll
        for (int r = 0; r < 4; r++) {
            float s = sc4[r];
            s += __shfl_xor(s, 1); s += __shfl_xor(s, 2);
            s += __shfl_xor(s, 4); s += __shfl_xor(s, 8);
            const int p = mt * 16 + quad * 4 + r;
            if (l16 == 0 && p < 196) {
                float e = __expf(sv + s);
                s_score[p] = e;
                esum += e;
            }
        }
    }
    // esum lives in l16==0 lanes (0,16,32,48); fold across quads -> lane 0
    esum += __shfl_xor(esum, 16);
    esum += __shfl_xor(esum, 32);
    if (lane == 0) s_red[wave] = esum;
    __syncthreads();   // barrier 2: e[p] + per-wave sums ready

    const float tot = s_red[0] + s_red[1] + s_red[2] + s_red[3];
    const float rtot = __builtin_amdgcn_rcpf(tot);
    if (tid < 196)
        out[131072 + (size_t)b * 196 + tid] = s_score[tid] * rtot;   // att_weights

    // ---- Phase D: context[c] = beta[c]/tot * sum_p img[p][c]*e[p] ----
    {
        const int c = lane & 31;
        const int po = wave * 2 + (lane >> 5);   // 0..7
        float acc = 0.0f;
#pragma unroll 5
        for (int j = 0; j < 25; j++) {
            const int p = po + j * 8;            // <=199; rows 196+ zeroed
            acc = __builtin_fmaf(bf2f(s_imgh[p * HSTR + c]), s_score[p], acc);
        }
        acc += __shfl_xor(acc, 32);
        if ((lane >> 5) == 0) s_ctx[wave][c] = acc;
    }
    __syncthreads();   // barrier 3: ctx partials ready
    if (tid < 32) {
        const float v = s_ctx[0][tid] + s_ctx[1][tid] + s_ctx[2][tid] + s_ctx[3][tid];
        out[(size_t)b * 32 + tid] = v * rtot * beta[(size_t)b * 32 + tid];
    }
}

extern "C" void kernel_launch(void* const* d_in, const int* in_sizes, int n_in,
                              void* d_out, int out_size, void* d_ws, size_t ws_size,
                              hipStream_t stream) {
    const float* img    = (const float*)d_in[0];
    const float* hidden = (const float*)d_in[1];
    const float* W_w    = (const float*)d_in[2];
    const float* W_b    = (const float*)d_in[3];
    const float* U_w    = (const float*)d_in[4];
    const float* U_b    = (const float*)d_in[5];
    const float* v_w    = (const float*)d_in[6];
    // d_in[7] = v_b: cancels in softmax
    const float* fb_w   = (const float*)d_in[8];
    const float* fb_b   = (const float*)d_in[9];
    float* out = (float*)d_out;

    float* uh_ws   = (float*)d_ws;                                 // 2 MB
    float* beta_ws = uh_ws + 4096 * 128;                           // 0.5 MB
    unsigned short* Bhi = (unsigned short*)(beta_ws + 4096 * 32);  // 160 KB
    unsigned short* Blo = Bhi + 81920;                             // 160 KB
    unsigned short* Whi = Blo + 81920;                             // 8 KB
    float* partial = (float*)(Whi + 4096);
    const size_t fixed_bytes = ((char*)partial) - ((char*)d_ws);

    int nsplit = 1, direct = 1;
    if (ws_size >= fixed_bytes + (size_t)256 * 4 * 2560 * 4) { nsplit = 4; direct = 0; }
    else if (ws_size >= fixed_bytes + (size_t)256 * 2 * 2560 * 4) { nsplit = 2; direct = 0; }
    else if (ws_size >= fixed_bytes + (size_t)256 * 1 * 2560 * 4) { nsplit = 1; direct = 0; }

    k0_split<<<dim3(336), dim3(256), 0, stream>>>(U_w, fb_w, W_w, Bhi, Blo, Whi);
    k1_gemm<<<dim3(256 * nsplit), dim3(256), 0, stream>>>(
        hidden, Bhi, Blo, U_b, W_b, fb_b, uh_ws, beta_ws, partial, nsplit, direct);
    if (!direct)
        k1b_reduce<<<dim3(2560), dim3(256), 0, stream>>>(
            partial, U_b, W_b, fb_b, uh_ws, beta_ws, nsplit);
    k2_attn<<<dim3(4096), dim3(256), 0, stream>>>(img, Whi, v_w, uh_ws, beta_ws, out);
}